// Round 1
// baseline (295.709 us; speedup 1.0000x reference)
//
#include <hip/hip_runtime.h>
#include <hip/hip_bf16.h>

#define NN 50000
#define EE 600000
#define HH 128
#define CC 40
#define NEG 0.1f
#define CAP 40   // padded-CSR capacity; P(deg>40) ~ 1e-10 for Binom(600k, 1/50k)

typedef __attribute__((ext_vector_type(8))) short bf16x8;
typedef __attribute__((ext_vector_type(4))) float f32x4;

__device__ __forceinline__ unsigned short f2bf(float f) {
    unsigned u = __float_as_uint(f);
    unsigned r = u + 0x7fffu + ((u >> 16) & 1u);
    return (unsigned short)(r >> 16);
}
__device__ __forceinline__ float bfhi(unsigned v) { return __uint_as_float(v & 0xFFFF0000u); }
__device__ __forceinline__ float bflo(unsigned v) { return __uint_as_float(v << 16); }

// ---------------- padded-CSR build: one edge per thread (max TLP) ----------------
__global__ void k_build(const int* __restrict__ src, const int* __restrict__ dst,
                        int* __restrict__ counts, int* __restrict__ csr) {
    int e = blockIdx.x * blockDim.x + threadIdx.x;
    if (e < EE) {
        int d = dst[e];
        if ((unsigned)d < (unsigned)NN) {
            int sl = atomicAdd(&counts[d], 1);
            if (sl < CAP) csr[d * CAP + sl] = src[e];
        }
    }
}

// ---------------- k_prep: weight swizzle + counts zero + x->bf16 cast ----------------
struct PrepArgs {
    const float* wsrc[8];
    unsigned short* wdst[8];
    int* counts;
    const float* x;
    unsigned* xb;
};

template <int DOUT, int DOUTP>
__device__ __forceinline__ void swz_one(const float* __restrict__ W,
                                        unsigned short* __restrict__ dstf, int idx) {
    int k = idx / DOUTP, n = idx % DOUTP;
    unsigned short val = (n < DOUT) ? f2bf(W[k * DOUT + n]) : (unsigned short)0;
    int kt = k >> 5, kin = k & 31, nt = n >> 4, nin = n & 15;
    int lane = ((kin >> 3) << 4) | nin;
    int j = kin & 7;
    int NT = DOUTP >> 4;
    dstf[(((kt * NT + nt) * 64) + lane) * 8 + j] = val;
}

// blocks 0..383: six 128x128 weights (+ counts zero); 384..431: two 128x40->48;
// 432..: xcast of x (fp32 -> packed bf16)
__global__ void k_prep(PrepArgs a) {
    int b = blockIdx.x;
    if (b < 384) {
        int tid = b * 256 + threadIdx.x;
        if (tid < NN) a.counts[tid] = 0;
        int which = b >> 6;
        int idx = (b & 63) * 256 + threadIdx.x;
        swz_one<HH, HH>(a.wsrc[which], a.wdst[which], idx);
    } else if (b < 432) {
        int bb = b - 384;
        int which = 6 + bb / 24;
        int idx = (bb % 24) * 256 + threadIdx.x;
        swz_one<CC, 48>(a.wsrc[which], a.wdst[which], idx);
    } else {
        int t = (b - 432) * 256 + threadIdx.x;
        if (t < NN * HH / 4) {
            float4 v = ((const float4*)a.x)[t];
            uint2 o;
            o.x = ((unsigned)f2bf(v.y) << 16) | f2bf(v.x);
            o.y = ((unsigned)f2bf(v.w) << 16) | f2bf(v.z);
            ((uint2*)a.xb)[t] = o;
        }
    }
}

// ---------------- layer kernel: latency-optimized gather + double GEMM + lrelu ----------------
// Block = 1024 thr = 16 waves = 16 nodes (1 per wave). Gather: lane = s*16 + gg,
// s = edge slot 0..3, gg = uint4 dim-group (full 256B row per round, phases merged).
// CSR row indices hoisted (all rounds loaded upfront, unconditional+clamped) so the
// csr->gather dependent chain is paid once per wave; 3-deep static pipeline (vA/vB/vC).
// Round-count branches are wave-uniform scalar (readfirstlane).
// MFMA: waves 0..7 each compute 1 of 8 column tiles.
// MODE 1 (layer 3): additionally stage lrelu'd 16x128 tile to LDS; waves 0..2 compute
// t = tile @ dec_Wl (16x48) fused.
template <int MODE>
__global__ __launch_bounds__(1024, 8) void k_layer(
    const unsigned short* __restrict__ hin,    // [N][128] bf16
    const int* __restrict__ counts, const int* __restrict__ csr,
    const unsigned short* __restrict__ B1f, const unsigned short* __restrict__ B2f,
    const float* __restrict__ bias, unsigned short* __restrict__ out,
    const unsigned short* __restrict__ Tf, unsigned short* __restrict__ tOut) {
    __shared__ unsigned lds[16][72];
    int wid = threadIdx.x >> 6;        // 0..15 = node within tile
    int lane = threadIdx.x & 63;
    int m0 = blockIdx.x * 16;
    int gg = lane & 15;                // 16B dim-group (dims gg*8 .. gg*8+7)
    int s = lane >> 4;                 // 4 edge slots
    const uint4* hw4 = (const uint4*)hin;

    int node = m0 + wid;
    int cnt = counts[node];
    cnt = cnt < CAP ? cnt : CAP;
    int beg = node * CAP;
    float sc = 1.0f / (float)(cnt > 0 ? cnt : 1);
    int sr = (__builtin_amdgcn_readfirstlane(cnt) + 3) >> 2;   // rounds (scalar, <=10)

    // hoisted CSR row loads: unconditional (always in-bounds of csr alloc), clamped
    // against poison so the gather addresses are always valid (values masked later).
    int row[10];
#pragma unroll
    for (int r = 0; r < 10; ++r) {
        int v = csr[beg + r * 4 + s];
        row[r] = ((unsigned)v < (unsigned)NN) ? v : 0;
    }

    float acc[8];
#pragma unroll
    for (int d = 0; d < 8; ++d) acc[d] = 0.f;

    uint4 vA, vB, vC;

#define ISS(R, V) \
    if (sr > (R)) V = hw4[((unsigned)row[R] << 4) + gg]
#define ACC8(R, V)                                            \
    if (sr > (R)) {                                           \
        if ((R) * 4 + s < cnt) {                              \
            acc[0] += bflo(V.x); acc[1] += bfhi(V.x);         \
            acc[2] += bflo(V.y); acc[3] += bfhi(V.y);         \
            acc[4] += bflo(V.z); acc[5] += bfhi(V.z);         \
            acc[6] += bflo(V.w); acc[7] += bfhi(V.w);         \
        }                                                     \
    }

    // 3-deep static software pipeline over up to 10 rounds (all reg indices literal)
    ISS(0, vA); ISS(1, vB); ISS(2, vC);
    ACC8(0, vA); ISS(3, vA);
    ACC8(1, vB); ISS(4, vB);
    ACC8(2, vC); ISS(5, vC);
    ACC8(3, vA); ISS(6, vA);
    ACC8(4, vB); ISS(7, vB);
    ACC8(5, vC); ISS(8, vC);
    ACC8(6, vA); ISS(9, vA);
    ACC8(7, vB);
    ACC8(8, vC);
    ACC8(9, vA);
#undef ISS
#undef ACC8

    // reduce over slot bits (lane bits 4,5) — 2 shuffle levels only
#pragma unroll
    for (int d = 0; d < 8; ++d) {
        float t = acc[d];
        t += __shfl_xor(t, 16, 64);
        t += __shfl_xor(t, 32, 64);
        acc[d] = t * sc;
    }
    if (lane < 16) {   // s == 0, gg == lane
        uint4 w4;
        w4.x = ((unsigned)f2bf(acc[1]) << 16) | f2bf(acc[0]);
        w4.y = ((unsigned)f2bf(acc[3]) << 16) | f2bf(acc[2]);
        w4.z = ((unsigned)f2bf(acc[5]) << 16) | f2bf(acc[4]);
        w4.w = ((unsigned)f2bf(acc[7]) << 16) | f2bf(acc[6]);
        *(uint4*)&lds[wid][gg * 4] = w4;
    }
    __syncthreads();

    // ---- MFMA: A1 from LDS, A2 = self row; waves 0..7, 1 col-tile per wave ----
    int nin = lane & 15;
    int kq = lane >> 4;
    unsigned short hv[4];

    if (wid < 8) {
        const unsigned* arow = &lds[nin][0];
        f32x4 acc1 = (f32x4){0.f, 0.f, 0.f, 0.f};

#pragma unroll
        for (int kt = 0; kt < 4; ++kt) {
            bf16x8 a1 = *(const bf16x8*)(arow + kt * 16 + kq * 4);
            bf16x8 a2 = *(const bf16x8*)(hin + (size_t)(m0 + nin) * HH + kt * 32 + kq * 8);
            bf16x8 b1 = *(const bf16x8*)(B1f + (((kt * 8 + wid) * 64) + lane) * 8);
            acc1 = __builtin_amdgcn_mfma_f32_16x16x32_bf16(a1, b1, acc1, 0, 0, 0);
            bf16x8 b2 = *(const bf16x8*)(B2f + (((kt * 8 + wid) * 64) + lane) * 8);
            acc1 = __builtin_amdgcn_mfma_f32_16x16x32_bf16(a2, b2, acc1, 0, 0, 0);
        }

        // C/D: col = lane&15, row = (lane>>4)*4 + reg
        int col = wid * 16 + nin;
        float bv = bias[col];
#pragma unroll
        for (int r = 0; r < 4; ++r) {
            int m = m0 + kq * 4 + r;
            float v = acc1[r] + bv;
            v = fmaxf(v, NEG * v);
            hv[r] = f2bf(v);
            out[(size_t)m * HH + col] = hv[r];
        }
    }

    if (MODE == 1) {
        // stage lrelu'd tile to LDS (all a1-frag reads complete), then waves 0..2
        // compute t = tile @ dec_Wl (3 col tiles of 16).
        __syncthreads();
        unsigned short* lsh = (unsigned short*)&lds[0][0];   // [16][144] shorts
        if (wid < 8) {
            int col = wid * 16 + nin;
#pragma unroll
            for (int r = 0; r < 4; ++r) lsh[(kq * 4 + r) * 144 + col] = hv[r];
        }
        __syncthreads();
        if (wid < 3) {
            f32x4 at = (f32x4){0.f, 0.f, 0.f, 0.f};
#pragma unroll
            for (int kt = 0; kt < 4; ++kt) {
                bf16x8 a = *(const bf16x8*)&lsh[nin * 144 + kt * 32 + kq * 8];
                bf16x8 b = *(const bf16x8*)(Tf + (((kt * 3 + wid) * 64) + lane) * 8);
                at = __builtin_amdgcn_mfma_f32_16x16x32_bf16(a, b, at, 0, 0, 0);
            }
#pragma unroll
            for (int r = 0; r < 4; ++r) {
                int m = m0 + kq * 4 + r;
                tOut[(size_t)m * 48 + wid * 16 + nin] = f2bf(at[r]);
            }
        }
    }
}

// ---------------- k_dec: gather t (96B rows) + h1@Wr + bias + log_softmax ----------------
// Same latency treatment: 1 node/wave, 16 waves, hoisted csr rows, 3-deep pipeline.
// lane = s*8 + g: 8 slots, g = uint4 group (6 real + 2 dup -> same cache lines).
__global__ __launch_bounds__(1024, 8) void k_dec(
    const unsigned short* __restrict__ tbuf,   // [N][48] bf16, 96B rows
    const unsigned short* __restrict__ h1,
    const int* __restrict__ counts, const int* __restrict__ csr,
    const unsigned short* __restrict__ B2f, const float* __restrict__ bias,
    float* __restrict__ out) {
    __shared__ float aggT[16][52];
    int wid = threadIdx.x >> 6;        // 0..15 = node within tile
    int lane = threadIdx.x & 63;
    int m0 = blockIdx.x * 16;
    int g = lane & 7;
    int g6 = g < 6 ? g : g - 6;
    int s = lane >> 3;                 // 8 edge-slots
    const uint4* t4 = (const uint4*)tbuf;

    int node = m0 + wid;
    int cnt = counts[node];
    cnt = cnt < CAP ? cnt : CAP;
    int beg = node * CAP;
    float sc = 1.0f / (float)(cnt > 0 ? cnt : 1);
    int sr = (__builtin_amdgcn_readfirstlane(cnt) + 7) >> 3;   // rounds (scalar, <=5)

    int row[5];
#pragma unroll
    for (int r = 0; r < 5; ++r) {
        int v = csr[beg + r * 8 + s];
        row[r] = ((unsigned)v < (unsigned)NN) ? v : 0;
    }

    float acc[8];
#pragma unroll
    for (int d = 0; d < 8; ++d) acc[d] = 0.f;

    uint4 vA, vB, vC;

#define ISSD(R, V) \
    if (sr > (R)) V = t4[(unsigned)row[R] * 6 + g6]
#define ACCD(R, V)                                            \
    if (sr > (R)) {                                           \
        if ((R) * 8 + s < cnt) {                              \
            acc[0] += bflo(V.x); acc[1] += bfhi(V.x);         \
            acc[2] += bflo(V.y); acc[3] += bfhi(V.y);         \
            acc[4] += bflo(V.z); acc[5] += bfhi(V.z);         \
            acc[6] += bflo(V.w); acc[7] += bfhi(V.w);         \
        }                                                     \
    }

    ISSD(0, vA); ISSD(1, vB); ISSD(2, vC);
    ACCD(0, vA); ISSD(3, vA);
    ACCD(1, vB); ISSD(4, vB);
    ACCD(2, vC);
    ACCD(3, vA);
    ACCD(4, vB);
#undef ISSD
#undef ACCD

    // reduce over slot bits (lane bits 3..5)
#pragma unroll
    for (int d = 0; d < 8; ++d) {
        float t = acc[d];
        t += __shfl_xor(t, 8, 64);
        t += __shfl_xor(t, 16, 64);
        t += __shfl_xor(t, 32, 64);
        acc[d] = t * sc;
    }
    if (s == 0 && g < 6) {
        float4 p0, p1;
        p0.x = acc[0]; p0.y = acc[1]; p0.z = acc[2]; p0.w = acc[3];
        p1.x = acc[4]; p1.y = acc[5]; p1.z = acc[6]; p1.w = acc[7];
        *(float4*)&aggT[wid][8 * g] = p0;
        *(float4*)&aggT[wid][8 * g + 4] = p1;
    }
    __syncthreads();
    if (wid != 0) return;

    int nin = lane & 15, kq = lane >> 4;
    f32x4 acc2[3];
#pragma unroll
    for (int j = 0; j < 3; ++j) acc2[j] = (f32x4){0.f, 0.f, 0.f, 0.f};
#pragma unroll
    for (int kt = 0; kt < 4; ++kt) {
        bf16x8 a2 = *(const bf16x8*)(h1 + (size_t)(m0 + nin) * HH + kt * 32 + kq * 8);
#pragma unroll
        for (int j = 0; j < 3; ++j) {
            bf16x8 b2 = *(const bf16x8*)(B2f + (((kt * 3 + j) * 64) + lane) * 8);
            acc2[j] = __builtin_amdgcn_mfma_f32_16x16x32_bf16(a2, b2, acc2[j], 0, 0, 0);
        }
    }
    float bv[3];
#pragma unroll
    for (int t = 0; t < 3; ++t) {
        int col = t * 16 + nin;
        bv[t] = (col < CC) ? bias[col] : 0.f;
    }
#pragma unroll
    for (int r = 0; r < 4; ++r) {
        int m = m0 + kq * 4 + r;
        int ml = kq * 4 + r;
        float v[3];
        float mx = -1e30f;
#pragma unroll
        for (int t = 0; t < 3; ++t) {
            int col = t * 16 + nin;
            v[t] = acc2[t][r] + aggT[ml][col] + bv[t];
            if (col < CC) mx = fmaxf(mx, v[t]);
        }
        for (int off = 1; off < 16; off <<= 1) mx = fmaxf(mx, __shfl_xor(mx, off, 64));
        float sm = 0.f;
#pragma unroll
        for (int t = 0; t < 3; ++t) {
            int col = t * 16 + nin;
            if (col < CC) sm += expf(v[t] - mx);
        }
        for (int off = 1; off < 16; off <<= 1) sm += __shfl_xor(sm, off, 64);
        float lse = mx + logf(sm);
#pragma unroll
        for (int t = 0; t < 3; ++t) {
            int col = t * 16 + nin;
            if (col < CC) out[(size_t)m * CC + col] = v[t] - lse;
        }
    }
}

extern "C" void kernel_launch(void* const* d_in, const int* in_sizes, int n_in,
                              void* d_out, int out_size, void* d_ws, size_t ws_size,
                              hipStream_t stream) {
    const float* x      = (const float*)d_in[0];
    const int*   ei     = (const int*)d_in[1];
    const float* enc_Wl = (const float*)d_in[2];
    const float* enc_Wr = (const float*)d_in[3];
    const float* enc_b  = (const float*)d_in[4];
    const float* lay_Wl = (const float*)d_in[5];
    const float* lay_Wr = (const float*)d_in[6];
    const float* lay_b  = (const float*)d_in[7];
    const float* dec_Wl = (const float*)d_in[8];
    const float* dec_Wr = (const float*)d_in[9];
    const float* dec_b  = (const float*)d_in[10];
    float* out = (float*)d_out;

    const int* src = ei;
    const int* dst = ei + EE;

    // ---- workspace carve (256B aligned), total ~39 MB ----
    char* p = (char*)d_ws;
    auto carve = [&](size_t bytes) {
        char* r = p;
        p += (bytes + 255) & ~(size_t)255;
        return r;
    };
    int*            counts = (int*)carve(NN * 4);
    int*            csr    = (int*)carve((size_t)NN * CAP * 4);
    unsigned short* h1     = (unsigned short*)carve((size_t)NN * HH * 2);
    unsigned short* h2     = (unsigned short*)carve((size_t)NN * HH * 2);  // also xb
    unsigned short* tbuf   = (unsigned short*)carve((size_t)NN * 48 * 2 + 256);  // +pad for g-dupe reads
    unsigned short* wf[8];
    for (int i = 0; i < 6; ++i) wf[i] = (unsigned short*)carve(HH * HH * 2);
    wf[6] = (unsigned short*)carve(HH * 48 * 2);
    wf[7] = (unsigned short*)carve(HH * 48 * 2);

    // prep: weight swizzles + counts zero + x->bf16 (one launch)
    {
        PrepArgs a;
        a.wsrc[0] = enc_Wl; a.wsrc[1] = enc_Wr;
        a.wsrc[2] = lay_Wl; a.wsrc[3] = lay_Wr;
        a.wsrc[4] = lay_Wl + HH * HH; a.wsrc[5] = lay_Wr + HH * HH;
        a.wsrc[6] = dec_Wl; a.wsrc[7] = dec_Wr;
        for (int i = 0; i < 8; ++i) a.wdst[i] = wf[i];
        a.counts = counts;
        a.x = x;
        a.xb = (unsigned*)h2;
        k_prep<<<432 + (NN * HH / 4 + 255) / 256, 256, 0, stream>>>(a);
    }

    // padded-CSR build: one edge per thread
    k_build<<<(EE + 255) / 256, 256, 0, stream>>>(src, dst, counts, csr);

    // layers: 3125 blocks x 16 waves (1 node/wave); layer 3 fuses t = h1 @ dec_Wl
    const int FB = NN / 16;   // 3125
    k_layer<0><<<FB, 1024, 0, stream>>>(h2, counts, csr, wf[0], wf[1], enc_b,      h1, nullptr, nullptr);
    k_layer<0><<<FB, 1024, 0, stream>>>(h1, counts, csr, wf[2], wf[3], lay_b,      h2, nullptr, nullptr);
    k_layer<1><<<FB, 1024, 0, stream>>>(h2, counts, csr, wf[4], wf[5], lay_b + HH, h1, wf[6], tbuf);

    // decoder: gather t + h1@Wr + log_softmax
    k_dec<<<FB, 1024, 0, stream>>>(tbuf, h1, counts, csr, wf[7], dec_b, out);
}